// Round 1
// baseline (861.786 us; speedup 1.0000x reference)
//
#include <hip/hip_runtime.h>
#include <math.h>

// Problem constants
#define B_    32
#define C_    256
#define HT_   56
#define WD_   56
#define HW_   3136          // 56*56
#define XSTR_ 802816        // 256*3136 (per-batch stride of x)
#define NH_   8
#define E_    32            // C/NH
#define N1_   768           // 3*C
#define NWIN_ 14            // 56/4 windows per side

// ---------------------------------------------------------------------------
// Kernel 1: qkv[m][n] = sum_k x[b][k][hw] * w1[n][k] + b1[n]
//   m = b*3136 + hw (M = 100352), n in [0,768), K = 256
//   Tiling: BM=BN=128, BK=16, 256 threads, 8x8 per thread.
// ---------------------------------------------------------------------------
__global__ __launch_bounds__(256) void qkv_gemm(
    const float* __restrict__ x, const float* __restrict__ w1,
    const float* __restrict__ b1, float* __restrict__ qkv) {
  __shared__ __align__(16) float As[16][132];
  __shared__ __align__(16) float Bs[16][132];

  const int t = threadIdx.x;
  // XCD-aware swizzle: 4704 blocks = 784 m-tiles x 6 n-tiles; keep the 6
  // n-tiles that share one A-tile on the same XCD (consecutive-by-8 ids).
  const int d   = blockIdx.x;
  const int xcd = d & 7;
  const int i   = d >> 3;          // 0..587
  const int bn  = i % 6;
  const int bmL = i / 6;           // 0..97
  const int bm  = bmL * 8 + xcd;   // 0..783
  const int m0 = bm * 128, n0 = bn * 128;

  // A loader: thread -> (kkA = t/32 in [0,8), fA = t%32 float4 along m)
  const int fA = t & 31, kkA = t >> 5;
  const int m4 = m0 + fA * 4;
  const int bb = m4 / HW_;
  const int hw = m4 - bb * HW_;
  const float* xA = x + bb * XSTR_ + hw;   // + k*3136 later

  // B loader: thread -> (nnB = t%128 row of w1 tile, fB = t/128 in {0,1})
  const int nnB = t & 127, fB = t >> 7;
  const float* w1r = w1 + (n0 + nnB) * 256;

  // Compute mapping: tn fastest (store coalescing), 16x16 threads, 8x8 each
  const int tn = t & 15, tm = t >> 4;

  float acc[8][8];
#pragma unroll
  for (int r = 0; r < 8; ++r)
#pragma unroll
    for (int c = 0; c < 8; ++c) acc[r][c] = 0.f;

  for (int k0 = 0; k0 < 256; k0 += 16) {
    float4 a0  = *(const float4*)(xA + (k0 + kkA) * HW_);
    float4 a1  = *(const float4*)(xA + (k0 + kkA + 8) * HW_);
    float4 bv0 = *(const float4*)(w1r + k0 + fB * 4);
    float4 bv1 = *(const float4*)(w1r + k0 + (fB + 2) * 4);

    *(float4*)&As[kkA][fA * 4]     = a0;
    *(float4*)&As[kkA + 8][fA * 4] = a1;
    Bs[fB * 4 + 0][nnB] = bv0.x;
    Bs[fB * 4 + 1][nnB] = bv0.y;
    Bs[fB * 4 + 2][nnB] = bv0.z;
    Bs[fB * 4 + 3][nnB] = bv0.w;
    Bs[(fB + 2) * 4 + 0][nnB] = bv1.x;
    Bs[(fB + 2) * 4 + 1][nnB] = bv1.y;
    Bs[(fB + 2) * 4 + 2][nnB] = bv1.z;
    Bs[(fB + 2) * 4 + 3][nnB] = bv1.w;
    __syncthreads();

#pragma unroll
    for (int kk = 0; kk < 16; ++kk) {
      float4 A0 = *(const float4*)&As[kk][tm * 8];
      float4 A1 = *(const float4*)&As[kk][tm * 8 + 4];
      float4 B0 = *(const float4*)&Bs[kk][tn * 8];
      float4 B1 = *(const float4*)&Bs[kk][tn * 8 + 4];
      float av[8] = {A0.x, A0.y, A0.z, A0.w, A1.x, A1.y, A1.z, A1.w};
      float bv[8] = {B0.x, B0.y, B0.z, B0.w, B1.x, B1.y, B1.z, B1.w};
#pragma unroll
      for (int r = 0; r < 8; ++r)
#pragma unroll
        for (int c = 0; c < 8; ++c) acc[r][c] = fmaf(av[r], bv[c], acc[r][c]);
    }
    __syncthreads();
  }

  const float4 bias0 = *(const float4*)&b1[n0 + tn * 8];
  const float4 bias1 = *(const float4*)&b1[n0 + tn * 8 + 4];
#pragma unroll
  for (int r = 0; r < 8; ++r) {
    const int m = m0 + tm * 8 + r;
    float* dst = qkv + (size_t)m * N1_ + n0 + tn * 8;
    float4 o0 = make_float4(acc[r][0] + bias0.x, acc[r][1] + bias0.y,
                            acc[r][2] + bias0.z, acc[r][3] + bias0.w);
    float4 o1 = make_float4(acc[r][4] + bias1.x, acc[r][5] + bias1.y,
                            acc[r][6] + bias1.z, acc[r][7] + bias1.w);
    *(float4*)dst       = o0;
    *(float4*)(dst + 4) = o1;
  }
}

// ---------------------------------------------------------------------------
// Kernel 2: shifted-window attention.
// One block = one window (b,wy,wx); 8 waves = 8 heads.
// qkv layout: [m][768] with n = e*24 + h*3 + k (k=0:Q,1:K,2:V), e in [0,32).
// Shift folded into the gather: src (y,x) = (wy*4+pr+2)%56, (wx*4+pc+2)%56.
// Output written UNSHIFTED (reference does not roll back) to
//   attn_out[b][y][x][h*32+e], y = wy*4+pr, x = wx*4+pc.
// ---------------------------------------------------------------------------
__global__ __launch_bounds__(512) void win_attn(
    const float* __restrict__ qkv, const float* __restrict__ pos,
    float* __restrict__ attn_out) {
  __shared__ __align__(16) float Qs[8][16][36];
  __shared__ __align__(16) float Ks[8][16][36];
  __shared__ __align__(16) float Vs[8][16][36];
  __shared__ float Sc[8][16][17];
  __shared__ float Pe[49];

  const int t = threadIdx.x;
  const int w = t >> 6;      // wave = head
  const int l = t & 63;

  if (t < 49) Pe[t] = pos[t];

  const int win = blockIdx.x;            // 0..6271
  const int wx  = win % NWIN_;
  const int tmp = win / NWIN_;
  const int wy  = tmp % NWIN_;
  const int b   = tmp / NWIN_;
  const int h   = w;

  // ---- gather Q,K,V (16 tokens x 32 chans) for this head into LDS ----
  const int e  = l & 31;
  const int ph = l >> 5;     // token parity handled by this lane
#pragma unroll
  for (int pp = 0; pp < 8; ++pp) {
    const int p  = pp * 2 + ph;
    const int pr = p >> 2, pc = p & 3;
    int y  = wy * 4 + pr + 2; if (y >= HT_) y -= HT_;
    int xx = wx * 4 + pc + 2; if (xx >= WD_) xx -= WD_;
    const size_t base = ((size_t)(b * HW_ + y * WD_ + xx)) * N1_ + e * 24 + h * 3;
    Qs[w][p][e] = qkv[base];
    Ks[w][p][e] = qkv[base + 1];
    Vs[w][p][e] = qkv[base + 2];
  }
  __syncthreads();

  // ---- scores: lane (p = l/4, qg = l%4) computes s[p][qg*4 + 0..3] ----
  const int p  = l >> 2, qg = l & 3;
  const int pr = p >> 2, pc = p & 3;
  float4 qv[8];
#pragma unroll
  for (int ii = 0; ii < 8; ++ii) qv[ii] = *(const float4*)&Qs[w][p][ii * 4];

  const float rscale = 0.17677669529663687f;   // 1/sqrt(32)
  float sv[4];
#pragma unroll
  for (int j = 0; j < 4; ++j) {
    const int q  = qg * 4 + j;
    const int qr = q >> 2, qc = q & 3;
    const float4* kr = (const float4*)&Ks[w][q][0];
    float dot = 0.f;
#pragma unroll
    for (int ii = 0; ii < 8; ++ii) {
      float4 kv = kr[ii];
      dot = fmaf(qv[ii].x, kv.x, dot);
      dot = fmaf(qv[ii].y, kv.y, dot);
      dot = fmaf(qv[ii].z, kv.z, dot);
      dot = fmaf(qv[ii].w, kv.w, dot);
    }
    float s = dot * rscale + Pe[(qr - pr + 3) * 7 + (qc - pc + 3)];
    // shift masks (only last window row / col)
    if (wy == NWIN_ - 1 && ((pr >= 2) != (qr >= 2))) s = -1e30f;
    if (wx == NWIN_ - 1 && ((pc >= 2) != (qc >= 2))) s = -1e30f;
    sv[j] = s;
  }

  // ---- softmax across the 4-lane group holding row p ----
  float mx = fmaxf(fmaxf(sv[0], sv[1]), fmaxf(sv[2], sv[3]));
  mx = fmaxf(mx, __shfl_xor(mx, 1));
  mx = fmaxf(mx, __shfl_xor(mx, 2));
  float ex[4], sm = 0.f;
#pragma unroll
  for (int j = 0; j < 4; ++j) { ex[j] = __expf(sv[j] - mx); sm += ex[j]; }
  sm += __shfl_xor(sm, 1);
  sm += __shfl_xor(sm, 2);
  const float inv = 1.0f / sm;
#pragma unroll
  for (int j = 0; j < 4; ++j) Sc[w][p][qg * 4 + j] = ex[j] * inv;
  __syncthreads();

  // ---- PV: lane (p = l/4, eg = (l%4)*8) computes out[p][eg..eg+7] ----
  const int eg = (l & 3) * 8;
  float4 o0 = make_float4(0.f, 0.f, 0.f, 0.f);
  float4 o1 = make_float4(0.f, 0.f, 0.f, 0.f);
#pragma unroll
  for (int q = 0; q < 16; ++q) {
    const float aw = Sc[w][p][q];
    float4 v0 = *(const float4*)&Vs[w][q][eg];
    float4 v1 = *(const float4*)&Vs[w][q][eg + 4];
    o0.x = fmaf(aw, v0.x, o0.x); o0.y = fmaf(aw, v0.y, o0.y);
    o0.z = fmaf(aw, v0.z, o0.z); o0.w = fmaf(aw, v0.w, o0.w);
    o1.x = fmaf(aw, v1.x, o1.x); o1.y = fmaf(aw, v1.y, o1.y);
    o1.z = fmaf(aw, v1.z, o1.z); o1.w = fmaf(aw, v1.w, o1.w);
  }
  const int y  = wy * 4 + pr;
  const int xx = wx * 4 + pc;
  float* dst = attn_out + ((size_t)(b * HW_ + y * WD_ + xx)) * C_ + h * 32 + eg;
  *(float4*)dst       = o0;
  *(float4*)(dst + 4) = o1;
}

// ---------------------------------------------------------------------------
// Kernel 3: out[m][n] = sum_k attn[m][k] * w2[n][k] + b2[n]
//   M = 100352, N = 256, K = 256. Same tiling as kernel 1.
// ---------------------------------------------------------------------------
__global__ __launch_bounds__(256) void proj_gemm(
    const float* __restrict__ a, const float* __restrict__ w2,
    const float* __restrict__ b2, float* __restrict__ out) {
  __shared__ __align__(16) float As[16][132];
  __shared__ __align__(16) float Bs[16][132];

  const int t = threadIdx.x;
  const int d   = blockIdx.x;          // 1568 blocks = 784 x 2
  const int xcd = d & 7;
  const int i   = d >> 3;              // 0..195
  const int bn  = i & 1;
  const int bmL = i >> 1;              // 0..97
  const int bm  = bmL * 8 + xcd;
  const int m0 = bm * 128, n0 = bn * 128;

  // A loader: rowA = t/4 in [0,64) (+64 for 2nd), fk = t%4 float4 along k
  const int rowA = t >> 2, fk = t & 3;
  const float* aA = a + (size_t)(m0 + rowA) * C_ + fk * 4;

  // B loader (w2 rows)
  const int nnB = t & 127, fB = t >> 7;
  const float* w2r = w2 + (n0 + nnB) * C_;

  const int tn = t & 15, tm = t >> 4;

  float acc[8][8];
#pragma unroll
  for (int r = 0; r < 8; ++r)
#pragma unroll
    for (int c = 0; c < 8; ++c) acc[r][c] = 0.f;

  for (int k0 = 0; k0 < 256; k0 += 16) {
    float4 a0  = *(const float4*)(aA + k0);
    float4 a1  = *(const float4*)(aA + 64 * C_ + k0);
    float4 bv0 = *(const float4*)(w2r + k0 + fB * 4);
    float4 bv1 = *(const float4*)(w2r + k0 + (fB + 2) * 4);

    As[fk * 4 + 0][rowA] = a0.x;
    As[fk * 4 + 1][rowA] = a0.y;
    As[fk * 4 + 2][rowA] = a0.z;
    As[fk * 4 + 3][rowA] = a0.w;
    As[fk * 4 + 0][rowA + 64] = a1.x;
    As[fk * 4 + 1][rowA + 64] = a1.y;
    As[fk * 4 + 2][rowA + 64] = a1.z;
    As[fk * 4 + 3][rowA + 64] = a1.w;
    Bs[fB * 4 + 0][nnB] = bv0.x;
    Bs[fB * 4 + 1][nnB] = bv0.y;
    Bs[fB * 4 + 2][nnB] = bv0.z;
    Bs[fB * 4 + 3][nnB] = bv0.w;
    Bs[(fB + 2) * 4 + 0][nnB] = bv1.x;
    Bs[(fB + 2) * 4 + 1][nnB] = bv1.y;
    Bs[(fB + 2) * 4 + 2][nnB] = bv1.z;
    Bs[(fB + 2) * 4 + 3][nnB] = bv1.w;
    __syncthreads();

#pragma unroll
    for (int kk = 0; kk < 16; ++kk) {
      float4 A0 = *(const float4*)&As[kk][tm * 8];
      float4 A1 = *(const float4*)&As[kk][tm * 8 + 4];
      float4 B0 = *(const float4*)&Bs[kk][tn * 8];
      float4 B1 = *(const float4*)&Bs[kk][tn * 8 + 4];
      float av[8] = {A0.x, A0.y, A0.z, A0.w, A1.x, A1.y, A1.z, A1.w};
      float bv[8] = {B0.x, B0.y, B0.z, B0.w, B1.x, B1.y, B1.z, B1.w};
#pragma unroll
      for (int r = 0; r < 8; ++r)
#pragma unroll
        for (int c = 0; c < 8; ++c) acc[r][c] = fmaf(av[r], bv[c], acc[r][c]);
    }
    __syncthreads();
  }

  const float4 bias0 = *(const float4*)&b2[n0 + tn * 8];
  const float4 bias1 = *(const float4*)&b2[n0 + tn * 8 + 4];
#pragma unroll
  for (int r = 0; r < 8; ++r) {
    const int m = m0 + tm * 8 + r;
    float* dst = out + (size_t)m * C_ + n0 + tn * 8;
    float4 o0 = make_float4(acc[r][0] + bias0.x, acc[r][1] + bias0.y,
                            acc[r][2] + bias0.z, acc[r][3] + bias0.w);
    float4 o1 = make_float4(acc[r][4] + bias1.x, acc[r][5] + bias1.y,
                            acc[r][6] + bias1.z, acc[r][7] + bias1.w);
    *(float4*)dst       = o0;
    *(float4*)(dst + 4) = o1;
  }
}

// ---------------------------------------------------------------------------
extern "C" void kernel_launch(void* const* d_in, const int* in_sizes, int n_in,
                              void* d_out, int out_size, void* d_ws, size_t ws_size,
                              hipStream_t stream) {
  const float* x   = (const float*)d_in[0];
  const float* w1  = (const float*)d_in[1];
  const float* b1  = (const float*)d_in[2];
  const float* w2  = (const float*)d_in[3];
  const float* b2  = (const float*)d_in[4];
  const float* pos = (const float*)d_in[5];
  float* out = (float*)d_out;

  float* qkv  = (float*)d_ws;                       // 100352*768 floats (308 MB)
  float* attn = qkv + (size_t)100352 * N1_;         // 100352*256 floats (103 MB)

  qkv_gemm<<<4704, 256, 0, stream>>>(x, w1, b1, qkv);
  win_attn<<<6272, 512, 0, stream>>>(qkv, pos, attn);
  proj_gemm<<<1568, 256, 0, stream>>>(attn, w2, b2, out);
}

// Round 2
// 351.757 us; speedup vs baseline: 2.4499x; 2.4499x over previous
//
#include <hip/hip_runtime.h>
#include <hip/hip_bf16.h>
#include <math.h>

typedef __attribute__((ext_vector_type(8))) short short8;
typedef __attribute__((ext_vector_type(4))) short short4_;
typedef __attribute__((ext_vector_type(4))) float f32x4;

#define B_    32
#define C_    256
#define HW_   3136
#define N1_   768
#define NWIN_ 14
#define M_    100352   // B*HW

__device__ __forceinline__ short bf16_of(float f) {
  union { __hip_bfloat16 h; short s; } u;
  u.h = __float2bfloat16(f);
  return u.s;
}

__device__ __forceinline__ void load_lds16(const void* g, void* l) {
  __builtin_amdgcn_global_load_lds(
      (const __attribute__((address_space(1))) unsigned int*)g,
      (__attribute__((address_space(3))) unsigned int*)l, 16, 0, 0);
}

__device__ __forceinline__ f32x4 mfma16x16x16bf16(short4_ a, short4_ b, f32x4 c) {
#if __has_builtin(__builtin_amdgcn_mfma_f32_16x16x16bf16_1k)
  return __builtin_amdgcn_mfma_f32_16x16x16bf16_1k(a, b, c, 0, 0, 0);
#else
  // register-only MFMA via asm; s_nop covers MFMA->VALU RAW hazard
  asm volatile("v_mfma_f32_16x16x16_bf16 %0, %1, %2, %0\n\ts_nop 7\n\ts_nop 7"
               : "+v"(c) : "v"(a), "v"(b));
  return c;
#endif
}

// ---------------------------------------------------------------------------
// Kernel 0: convert weights to bf16 (w1: 768x256, w2: 256x256), layouts kept.
// ---------------------------------------------------------------------------
__global__ void conv_weights(const float* __restrict__ w1, const float* __restrict__ w2,
                             short* __restrict__ w1b, short* __restrict__ w2b) {
  int i = blockIdx.x * 256 + threadIdx.x;
  if (i < 196608) w1b[i] = bf16_of(w1[i]);
  if (i < 65536)  w2b[i] = bf16_of(w2[i]);
}

// ---------------------------------------------------------------------------
// Kernel 1: transpose+convert x[b][c][hw] f32 -> xt[m][c] bf16 (m = b*3136+hw)
// Tile: 64 tokens x 256 channels per block (3136/64 = 49, no b-crossing).
// ---------------------------------------------------------------------------
__global__ __launch_bounds__(256) void transpose_x(const float* __restrict__ x,
                                                   short* __restrict__ xt) {
  __shared__ short T[64 * 258];   // row stride 258 bf16 (129 dwords): ~2-way banks
  const int t = threadIdx.x;
  const int m0 = blockIdx.x * 64;
  const int b  = m0 / HW_;
  const int hw0 = m0 - b * HW_;

  for (int it = 0; it < 16; ++it) {
    const int c = it * 16 + (t >> 4);
    const int hw4 = (t & 15) * 4;
    float4 v = *(const float4*)(x + ((size_t)b * C_ + c) * HW_ + hw0 + hw4);
    T[(hw4 + 0) * 258 + c] = bf16_of(v.x);
    T[(hw4 + 1) * 258 + c] = bf16_of(v.y);
    T[(hw4 + 2) * 258 + c] = bf16_of(v.z);
    T[(hw4 + 3) * 258 + c] = bf16_of(v.w);
  }
  __syncthreads();
  for (int it = 0; it < 8; ++it) {
    const int idx = it * 256 + t;
    const int row = idx >> 5, ch = idx & 31;     // 16B chunk within row
    const short* rp = &T[row * 258 + ch * 8];
    int4 o;
    o.x = *(const int*)(rp + 0);
    o.y = *(const int*)(rp + 2);
    o.z = *(const int*)(rp + 4);
    o.w = *(const int*)(rp + 6);
    *(int4*)(xt + (size_t)(m0 + row) * C_ + ch * 8) = o;
  }
}

// ---------------------------------------------------------------------------
// bf16 MFMA GEMM core: C[M][N] = A[M][256] * B[N][256]^T (+bias).
// BM=BN=128, BK=64, 256 thr (4 waves, 2x2), wave = 64x64 = 4x4 frags 16x16x32.
// LDS tiles [128 rows][64 k] bf16, XOR-swizzled chunks (T2 st-style):
// LDS chunk c of row r holds source k-chunk (c ^ (r&7)).
// ---------------------------------------------------------------------------
__global__ __launch_bounds__(256) void qkv_gemm(const short* __restrict__ xt,
    const short* __restrict__ w1b, const float* __restrict__ b1,
    short* __restrict__ qkvb) {
  __shared__ char smem[32768];
  char* As = smem;
  char* Bs = smem + 16384;
  const int t = threadIdx.x, l = t & 63, w = t >> 6;
  const int d = blockIdx.x, xcd = d & 7, i0 = d >> 3;
  const int bn = i0 % 6, bm = (i0 / 6) * 8 + xcd;   // 6 n-tiles / A-tile per XCD
  const int m0 = bm * 128, n0 = bn * 128;
  const int lane = l & 15, kg = l >> 4;
  const int wm = w >> 1, wn = w & 1;

  f32x4 acc[4][4];
#pragma unroll
  for (int i = 0; i < 4; ++i)
#pragma unroll
    for (int j = 0; j < 4; ++j) acc[i][j] = (f32x4){0.f, 0.f, 0.f, 0.f};

  for (int ks = 0; ks < 4; ++ks) {
    const int k0 = ks * 64;
#pragma unroll
    for (int q = 0; q < 4; ++q) {
      const int row = (w * 4 + q) * 8 + (l >> 3);
      const int sc  = (l & 7) ^ (row & 7);
      load_lds16(xt  + (size_t)(m0 + row) * 256 + k0 + sc * 8, As + (w * 4 + q) * 1024);
      load_lds16(w1b + (size_t)(n0 + row) * 256 + k0 + sc * 8, Bs + (w * 4 + q) * 1024);
    }
    __syncthreads();
#pragma unroll
    for (int s = 0; s < 2; ++s) {
      short8 a[4], b[4];
#pragma unroll
      for (int i = 0; i < 4; ++i) {
        const int r = wm * 64 + i * 16 + lane;
        a[i] = *(const short8*)(As + r * 128 + ((s * 64 + kg * 16) ^ ((r & 7) << 4)));
      }
#pragma unroll
      for (int j = 0; j < 4; ++j) {
        const int r = wn * 64 + j * 16 + lane;
        b[j] = *(const short8*)(Bs + r * 128 + ((s * 64 + kg * 16) ^ ((r & 7) << 4)));
      }
#pragma unroll
      for (int i = 0; i < 4; ++i)
#pragma unroll
        for (int j = 0; j < 4; ++j)
          acc[i][j] = __builtin_amdgcn_mfma_f32_16x16x32_bf16(a[i], b[j], acc[i][j], 0, 0, 0);
    }
    __syncthreads();
  }

#pragma unroll
  for (int j = 0; j < 4; ++j) {
    const int n = n0 + wn * 64 + j * 16 + lane;
    const float bias = b1[n];
#pragma unroll
    for (int i = 0; i < 4; ++i) {
      const int mb = m0 + wm * 64 + i * 16 + kg * 4;
#pragma unroll
      for (int r = 0; r < 4; ++r)
        qkvb[(size_t)(mb + r) * N1_ + n] = bf16_of(acc[i][j][r] + bias);
    }
  }
}

// ---------------------------------------------------------------------------
// Kernel 3: shifted-window attention, bf16 MFMA.
// Block = window (b,wy,wx), 512 thr = 8 waves = 8 heads.
// qkvb channel for (h,e,k): n = 24e + 3h + k  (c = e*8+h, n = 3c+k).
// S^T = mfma(Kfrag, Qfrag): lane holds S^T[q=4*kg+r][p=lane]; softmax over q
// is in-lane 4-reduce + shfl_xor 16,32; P feeds PV's A-operand directly.
// ---------------------------------------------------------------------------
__global__ __launch_bounds__(512) void win_attn(const short* __restrict__ qkvb,
    const float* __restrict__ pos, short* __restrict__ attnb) {
  __shared__ short Sq[16 * 776];   // 16 tokens x 768 (+8 pad) bf16
  __shared__ short Ot[16 * 272];   // 16 tokens x 256 (+16 pad) bf16
  __shared__ float Pe[49];

  const int t = threadIdx.x, l = t & 63, h = t >> 6;
  if (t < 49) Pe[t] = pos[t];

  const int win = blockIdx.x;
  const int wxi = win % NWIN_;
  const int wyi = (win / NWIN_) % NWIN_;
  const int b   = win / (NWIN_ * NWIN_);

  // stage 16 shifted tokens' full qkv rows (1536 B each), coalesced
#pragma unroll
  for (int rep = 0; rep < 3; ++rep) {
    const int idx = rep * 512 + t;
    const int row = idx / 96, ch = idx % 96;
    const int pr = row >> 2, pc = row & 3;
    int y  = wyi * 4 + pr + 2; if (y >= 56) y -= 56;
    int xx = wxi * 4 + pc + 2; if (xx >= 56) xx -= 56;
    const size_t m = (size_t)b * HW_ + y * 56 + xx;
    int4 v = *(const int4*)(qkvb + m * N1_ + ch * 8);
    *(int4*)(Sq + row * 776 + ch * 8) = v;
  }
  __syncthreads();

  const int lane = l & 15, kg = l >> 4;

  // Q/K fragments: token = lane, e-slice = kg*8..+8
  short8 qf, kf;
  const short* rowp = Sq + lane * 776;
#pragma unroll
  for (int j = 0; j < 8; ++j) {
    const int e = kg * 8 + j;
    const int cq = 24 * e + 3 * h;
    qf[j] = rowp[cq];
    kf[j] = rowp[cq + 1];
  }
  f32x4 z = {0.f, 0.f, 0.f, 0.f};
  f32x4 st = __builtin_amdgcn_mfma_f32_16x16x32_bf16(kf, qf, z, 0, 0, 0);

  // scores + bias + masks; lane holds S^T[q=4kg+r][p=lane]
  const int pr = lane >> 2, pc = lane & 3;
  const float rscale = 0.17677669529663687f;  // 1/sqrt(32)
  float sv[4];
#pragma unroll
  for (int r = 0; r < 4; ++r) {
    const int q = kg * 4 + r, qr = q >> 2, qc = q & 3;
    float s = st[r] * rscale + Pe[(qr - pr + 3) * 7 + (qc - pc + 3)];
    if (wyi == NWIN_ - 1 && ((pr >= 2) != (qr >= 2))) s = -1e30f;
    if (wxi == NWIN_ - 1 && ((pc >= 2) != (qc >= 2))) s = -1e30f;
    sv[r] = s;
  }
  // softmax over q (16 values spread over 4 regs x lanes {l, l^16, l^32, l^48})
  float mx = fmaxf(fmaxf(sv[0], sv[1]), fmaxf(sv[2], sv[3]));
  mx = fmaxf(mx, __shfl_xor(mx, 16));
  mx = fmaxf(mx, __shfl_xor(mx, 32));
  float ex[4], sm = 0.f;
#pragma unroll
  for (int r = 0; r < 4; ++r) { ex[r] = __expf(sv[r] - mx); sm += ex[r]; }
  sm += __shfl_xor(sm, 16);
  sm += __shfl_xor(sm, 32);
  const float inv = 1.0f / sm;
  short4_ pf;
#pragma unroll
  for (int r = 0; r < 4; ++r) pf[r] = bf16_of(ex[r] * inv);

  // PV: two 16x16x16 MFMAs (e-halves); V slot (kg,i) = token 4kg+i (matches P)
#pragma unroll
  for (int half = 0; half < 2; ++half) {
    short4_ vf;
#pragma unroll
    for (int i = 0; i < 4; ++i) {
      const int vrow = kg * 4 + i;
      const int e = half * 16 + lane;
      vf[i] = Sq[vrow * 776 + 24 * e + 3 * h + 2];
    }
    f32x4 o = mfma16x16x16bf16(pf, vf, z);
    // lane holds O[p=4kg+r][e=half*16+lane]
#pragma unroll
    for (int r = 0; r < 4; ++r)
      Ot[(kg * 4 + r) * 272 + h * 32 + half * 16 + lane] = bf16_of(o[r]);
  }
  __syncthreads();

  // coalesced write-out (unshifted coords), one int4 per thread
  const int row = t >> 5, ch = t & 31;
  const short* rp = &Ot[row * 272 + ch * 8];
  int4 v = *(const int4*)rp;
  const size_t mo = (size_t)b * HW_ + (wyi * 4 + (row >> 2)) * 56 + wxi * 4 + (row & 3);
  *(int4*)(attnb + mo * C_ + ch * 8) = v;
}

// ---------------------------------------------------------------------------
// Kernel 4: out[m][n] = attn[m][:] . w2[n][:] + b2[n], fp32 out. Same core.
// ---------------------------------------------------------------------------
__global__ __launch_bounds__(256) void proj_gemm(const short* __restrict__ attnb,
    const short* __restrict__ w2b, const float* __restrict__ b2,
    float* __restrict__ out) {
  __shared__ char smem[32768];
  char* As = smem;
  char* Bs = smem + 16384;
  const int t = threadIdx.x, l = t & 63, w = t >> 6;
  const int d = blockIdx.x, xcd = d & 7, i0 = d >> 3;
  const int bn = i0 & 1, bm = (i0 >> 1) * 8 + xcd;
  const int m0 = bm * 128, n0 = bn * 128;
  const int lane = l & 15, kg = l >> 4;
  const int wm = w >> 1, wn = w & 1;

  f32x4 acc[4][4];
#pragma unroll
  for (int i = 0; i < 4; ++i)
#pragma unroll
    for (int j = 0; j < 4; ++j) acc[i][j] = (f32x4){0.f, 0.f, 0.f, 0.f};

  for (int ks = 0; ks < 4; ++ks) {
    const int k0 = ks * 64;
#pragma unroll
    for (int q = 0; q < 4; ++q) {
      const int row = (w * 4 + q) * 8 + (l >> 3);
      const int sc  = (l & 7) ^ (row & 7);
      load_lds16(attnb + (size_t)(m0 + row) * 256 + k0 + sc * 8, As + (w * 4 + q) * 1024);
      load_lds16(w2b   + (size_t)(n0 + row) * 256 + k0 + sc * 8, Bs + (w * 4 + q) * 1024);
    }
    __syncthreads();
#pragma unroll
    for (int s = 0; s < 2; ++s) {
      short8 a[4], b[4];
#pragma unroll
      for (int i = 0; i < 4; ++i) {
        const int r = wm * 64 + i * 16 + lane;
        a[i] = *(const short8*)(As + r * 128 + ((s * 64 + kg * 16) ^ ((r & 7) << 4)));
      }
#pragma unroll
      for (int j = 0; j < 4; ++j) {
        const int r = wn * 64 + j * 16 + lane;
        b[j] = *(const short8*)(Bs + r * 128 + ((s * 64 + kg * 16) ^ ((r & 7) << 4)));
      }
#pragma unroll
      for (int i = 0; i < 4; ++i)
#pragma unroll
        for (int j = 0; j < 4; ++j)
          acc[i][j] = __builtin_amdgcn_mfma_f32_16x16x32_bf16(a[i], b[j], acc[i][j], 0, 0, 0);
    }
    __syncthreads();
  }

#pragma unroll
  for (int j = 0; j < 4; ++j) {
    const int n = n0 + wn * 64 + j * 16 + lane;
    const float bias = b2[n];
#pragma unroll
    for (int i = 0; i < 4; ++i) {
      const int mb = m0 + wm * 64 + i * 16 + kg * 4;
#pragma unroll
      for (int r = 0; r < 4; ++r)
        out[(size_t)(mb + r) * C_ + n] = acc[i][j][r] + bias;
    }
  }
}

// ---------------------------------------------------------------------------
extern "C" void kernel_launch(void* const* d_in, const int* in_sizes, int n_in,
                              void* d_out, int out_size, void* d_ws, size_t ws_size,
                              hipStream_t stream) {
  const float* x   = (const float*)d_in[0];
  const float* w1  = (const float*)d_in[1];
  const float* b1  = (const float*)d_in[2];
  const float* w2  = (const float*)d_in[3];
  const float* b2  = (const float*)d_in[4];
  const float* pos = (const float*)d_in[5];
  float* out = (float*)d_out;

  char* ws = (char*)d_ws;
  short* xt    = (short*)ws;                                  // 100352*256
  short* qkvb  = (short*)(ws + (size_t)52000000);             // 100352*768
  short* attnb = (short*)(ws + (size_t)52000000 + 155000000); // 100352*256
  short* w1b   = (short*)(ws + (size_t)52000000 + 155000000 + 52000000);
  short* w2b   = w1b + 196608;

  conv_weights<<<768, 256, 0, stream>>>(w1, w2, w1b, w2b);
  transpose_x <<<1568, 256, 0, stream>>>(x, xt);
  qkv_gemm    <<<4704, 256, 0, stream>>>(xt, w1b, b1, qkvb);
  win_attn    <<<6272, 512, 0, stream>>>(qkvb, pos, attnb);
  proj_gemm   <<<1568, 256, 0, stream>>>(attnb, w2b, b2, out);
}

// Round 9
// 349.825 us; speedup vs baseline: 2.4635x; 1.0055x over previous
//
#include <hip/hip_runtime.h>
#include <hip/hip_bf16.h>
#include <math.h>

typedef __attribute__((ext_vector_type(8))) short short8;
typedef __attribute__((ext_vector_type(4))) short short4_;
typedef __attribute__((ext_vector_type(4))) float f32x4;

#define B_    32
#define C_    256
#define HW_   3136
#define N1_   768
#define NWIN_ 14
#define M_    100352   // B*HW

__device__ __forceinline__ short bf16_of(float f) {
  union { __hip_bfloat16 h; short s; } u;
  u.h = __float2bfloat16(f);
  return u.s;
}

__device__ __forceinline__ void load_lds16(const void* g, void* l) {
  __builtin_amdgcn_global_load_lds(
      (const __attribute__((address_space(1))) unsigned int*)g,
      (__attribute__((address_space(3))) unsigned int*)l, 16, 0, 0);
}

__device__ __forceinline__ f32x4 mfma16x16x16bf16(short4_ a, short4_ b, f32x4 c) {
#if __has_builtin(__builtin_amdgcn_mfma_f32_16x16x16bf16_1k)
  return __builtin_amdgcn_mfma_f32_16x16x16bf16_1k(a, b, c, 0, 0, 0);
#else
  asm volatile("v_mfma_f32_16x16x16_bf16 %0, %1, %2, %0\n\ts_nop 7\n\ts_nop 7"
               : "+v"(c) : "v"(a), "v"(b));
  return c;
#endif
}

// ---------------------------------------------------------------------------
// Kernel 0: weight conversion + QKV-column permutation.
// New qkv channel order: n' = k*256 + h*32 + e  (orig n = 24e + 3h + k).
// ---------------------------------------------------------------------------
__global__ void conv_weights(const float* __restrict__ w1, const float* __restrict__ w2,
                             const float* __restrict__ b1,
                             short* __restrict__ w1p, short* __restrict__ w2b,
                             float* __restrict__ b1p) {
  int i = blockIdx.x * 256 + threadIdx.x;
  if (i < 196608) {
    const int r = i >> 8, c = i & 255;
    const int k = r >> 8, rem = r & 255, h = rem >> 5, e = rem & 31;
    const int orig = 24 * e + 3 * h + k;
    w1p[i] = bf16_of(w1[orig * 256 + c]);
  }
  if (i < 65536) w2b[i] = bf16_of(w2[i]);
  if (i < 768) {
    const int k = i >> 8, rem = i & 255, h = rem >> 5, e = rem & 31;
    b1p[i] = b1[24 * e + 3 * h + k];
  }
}

// ---------------------------------------------------------------------------
// Kernel 1: transpose+convert x[b][c][hw] f32 -> xt[m][c] bf16.
// 64 tokens x 256 chans per block. Register 4x4 transpose -> ds_write_b64,
// LDS chunk swizzle s=(row>>2)&7 on 8B chunks (2-way max both phases).
// Readout: 32 x 16B units per row (it<8, row=idx>>5, ch16=idx&31, dst ch16*8)
// -- R3 had it<4/idx>>4/&15/ch16*16, which left odd 16B units unwritten.
// ---------------------------------------------------------------------------
__global__ __launch_bounds__(256) void transpose_x(const float* __restrict__ x,
                                                   short* __restrict__ xt) {
  __shared__ __align__(16) short T[64 * 256];
  const int t = threadIdx.x;
  const int m0 = blockIdx.x * 64;
  const int b  = m0 / HW_;
  const int hw0 = m0 - b * HW_;
  const int tq = (t & 15) * 4;   // token base (4 tokens per thread)
  const int cg = t >> 4;         // 0..15 chan-quad group

#pragma unroll
  for (int p = 0; p < 4; ++p) {
    const int cc = (p * 16 + cg) * 4;            // chan base (mult of 4)
    const float* xp = x + ((size_t)b * C_ + cc) * HW_ + hw0 + tq;
    float4 v0 = *(const float4*)(xp);
    float4 v1 = *(const float4*)(xp + HW_);
    float4 v2 = *(const float4*)(xp + 2 * HW_);
    float4 v3 = *(const float4*)(xp + 3 * HW_);
    const int cq = p * 16 + cg;                  // 8B-chunk index (0..63)
#define WR_(i, e0, e1, e2, e3)                                        \
    { const int row = tq + i;                                         \
      short4_ wv; wv[0] = bf16_of(e0); wv[1] = bf16_of(e1);           \
      wv[2] = bf16_of(e2); wv[3] = bf16_of(e3);                       \
      *(short4_*)&T[row * 256 + ((cq ^ ((row >> 2) & 7)) << 2)] = wv; }
    WR_(0, v0.x, v1.x, v2.x, v3.x)
    WR_(1, v0.y, v1.y, v2.y, v3.y)
    WR_(2, v0.z, v1.z, v2.z, v3.z)
    WR_(3, v0.w, v1.w, v2.w, v3.w)
#undef WR_
  }
  __syncthreads();

#pragma unroll
  for (int it = 0; it < 8; ++it) {
    const int idx = it * 256 + t;
    const int row = idx >> 5, ch16 = idx & 31;   // 16B unit within row (0..31)
    const int s = (row >> 2) & 7;
    const int cqa = (ch16 * 2) ^ s, cqb = (ch16 * 2 + 1) ^ s;
    int2 lo = *(const int2*)&T[row * 256 + cqa * 4];
    int2 hi = *(const int2*)&T[row * 256 + cqb * 4];
    int4 o = make_int4(lo.x, lo.y, hi.x, hi.y);
    *(int4*)(xt + (size_t)(m0 + row) * C_ + ch16 * 8) = o;
  }
}

// ---------------------------------------------------------------------------
// Kernel 2: qkv GEMM (bf16 MFMA), BM=BN=128, BK=64, output uses permuted w1.
// ---------------------------------------------------------------------------
__global__ __launch_bounds__(256) void qkv_gemm(const short* __restrict__ xt,
    const short* __restrict__ w1p, const float* __restrict__ b1p,
    short* __restrict__ qkvb) {
  __shared__ char smem[32768];
  char* As = smem;
  char* Bs = smem + 16384;
  const int t = threadIdx.x, l = t & 63, w = t >> 6;
  const int d = blockIdx.x, xcd = d & 7, i0 = d >> 3;
  const int bn = i0 % 6, bm = (i0 / 6) * 8 + xcd;
  const int m0 = bm * 128, n0 = bn * 128;
  const int lane = l & 15, kg = l >> 4;
  const int wm = w >> 1, wn = w & 1;

  f32x4 acc[4][4];
#pragma unroll
  for (int i = 0; i < 4; ++i)
#pragma unroll
    for (int j = 0; j < 4; ++j) acc[i][j] = (f32x4){0.f, 0.f, 0.f, 0.f};

  for (int ks = 0; ks < 4; ++ks) {
    const int k0 = ks * 64;
#pragma unroll
    for (int q = 0; q < 4; ++q) {
      const int row = (w * 4 + q) * 8 + (l >> 3);
      const int sc  = (l & 7) ^ (row & 7);
      load_lds16(xt  + (size_t)(m0 + row) * 256 + k0 + sc * 8, As + (w * 4 + q) * 1024);
      load_lds16(w1p + (size_t)(n0 + row) * 256 + k0 + sc * 8, Bs + (w * 4 + q) * 1024);
    }
    __syncthreads();
#pragma unroll
    for (int s = 0; s < 2; ++s) {
      short8 a[4], b[4];
#pragma unroll
      for (int i = 0; i < 4; ++i) {
        const int r = wm * 64 + i * 16 + lane;
        a[i] = *(const short8*)(As + r * 128 + ((s * 64 + kg * 16) ^ ((r & 7) << 4)));
      }
#pragma unroll
      for (int j = 0; j < 4; ++j) {
        const int r = wn * 64 + j * 16 + lane;
        b[j] = *(const short8*)(Bs + r * 128 + ((s * 64 + kg * 16) ^ ((r & 7) << 4)));
      }
#pragma unroll
      for (int i = 0; i < 4; ++i)
#pragma unroll
        for (int j = 0; j < 4; ++j)
          acc[i][j] = __builtin_amdgcn_mfma_f32_16x16x32_bf16(a[i], b[j], acc[i][j], 0, 0, 0);
    }
    __syncthreads();
  }

#pragma unroll
  for (int j = 0; j < 4; ++j) {
    const int n = n0 + wn * 64 + j * 16 + lane;
    const float bias = b1p[n];
#pragma unroll
    for (int i = 0; i < 4; ++i) {
      const int mb = m0 + wm * 64 + i * 16 + kg * 4;
#pragma unroll
      for (int r = 0; r < 4; ++r)
        qkvb[(size_t)(mb + r) * N1_ + n] = bf16_of(acc[i][j][r] + bias);
    }
  }
}

// ---------------------------------------------------------------------------
// Kernel 3: shifted-window attention. qkvb layout n' = k*256 + h*32 + e.
// LDS Sq: 16 rows x 768 bf16, 16B-chunk XOR swizzle c' = c ^ (row&7).
// Q/K fragments are single ds_read_b128; V is 8 scalar reads.
// MFMA slot math identical to R2 (verified passing).
// ---------------------------------------------------------------------------
__global__ __launch_bounds__(512) void win_attn(const short* __restrict__ qkvb,
    const float* __restrict__ pos, short* __restrict__ attnb) {
  __shared__ __align__(16) short Sq[16 * 768];
  __shared__ __align__(16) short Ot[16 * 272];
  __shared__ float Pe[49];

  const int t = threadIdx.x, l = t & 63, h = t >> 6;
  if (t < 49) Pe[t] = pos[t];

  const int win = blockIdx.x;
  const int wxi = win % NWIN_;
  const int wyi = (win / NWIN_) % NWIN_;
  const int b   = win / (NWIN_ * NWIN_);

  // stage 16 shifted tokens' qkv rows (1536 B each), swizzled 16B chunks
#pragma unroll
  for (int rep = 0; rep < 3; ++rep) {
    const int idx = rep * 512 + t;
    const int row = idx / 96, ch = idx % 96;
    const int pr = row >> 2, pc = row & 3;
    int y  = wyi * 4 + pr + 2; if (y >= 56) y -= 56;
    int xx = wxi * 4 + pc + 2; if (xx >= 56) xx -= 56;
    const size_t m = (size_t)b * HW_ + y * 56 + xx;
    int4 v = *(const int4*)(qkvb + m * N1_ + ch * 8);
    *(int4*)(Sq + row * 768 + (ch ^ (row & 7)) * 8) = v;
  }
  __syncthreads();

  const int lane = l & 15, kg = l >> 4;

  // Q/K fragments: token = lane, e-slice kg*8..+8 -> one b128 each
  const int cQ = h * 4 + kg;
  short8 qf = *(const short8*)(Sq + lane * 768 + ((cQ)      ^ (lane & 7)) * 8);
  short8 kf = *(const short8*)(Sq + lane * 768 + ((32 + cQ) ^ (lane & 7)) * 8);

  f32x4 z = {0.f, 0.f, 0.f, 0.f};
  f32x4 st = __builtin_amdgcn_mfma_f32_16x16x32_bf16(kf, qf, z, 0, 0, 0);

  const int pr = lane >> 2, pc = lane & 3;
  const float rscale = 0.17677669529663687f;  // 1/sqrt(32)
  float sv[4];
#pragma unroll
  for (int r = 0; r < 4; ++r) {
    const int q = kg * 4 + r, qr = q >> 2, qc = q & 3;
    float s = st[r] * rscale + Pe[(qr - pr + 3) * 7 + (qc - pc + 3)];
    if (wyi == NWIN_ - 1 && ((pr >= 2) != (qr >= 2))) s = -1e30f;
    if (wxi == NWIN_ - 1 && ((pc >= 2) != (qc >= 2))) s = -1e30f;
    sv[r] = s;
  }
  float mx = fmaxf(fmaxf(sv[0], sv[1]), fmaxf(sv[2], sv[3]));
  mx = fmaxf(mx, __shfl_xor(mx, 16));
  mx = fmaxf(mx, __shfl_xor(mx, 32));
  float ex[4], sm = 0.f;
#pragma unroll
  for (int r = 0; r < 4; ++r) { ex[r] = __expf(sv[r] - mx); sm += ex[r]; }
  sm += __shfl_xor(sm, 16);
  sm += __shfl_xor(sm, 32);
  const float inv = 1.0f / sm;
  short4_ pf;
#pragma unroll
  for (int r = 0; r < 4; ++r) pf[r] = bf16_of(ex[r] * inv);

  // PV: V[token=kg*4+i][e = half*16+lane] at short index 512+h*32+half*16+lane
#pragma unroll
  for (int half = 0; half < 2; ++half) {
    short4_ vf;
    const int cV = 64 + h * 4 + half * 2 + (lane >> 3);   // 16B chunk
    const int el = lane & 7;
#pragma unroll
    for (int i = 0; i < 4; ++i) {
      const int vrow = kg * 4 + i;
      vf[i] = Sq[vrow * 768 + (cV ^ (vrow & 7)) * 8 + el];
    }
    f32x4 o = mfma16x16x16bf16(pf, vf, z);
#pragma unroll
    for (int r = 0; r < 4; ++r)
      Ot[(kg * 4 + r) * 272 + h * 32 + half * 16 + lane] = bf16_of(o[r]);
  }
  __syncthreads();

  const int row = t >> 5, ch = t & 31;
  const short* rp = &Ot[row * 272 + ch * 8];
  int4 v = *(const int4*)rp;
  const size_t mo = (size_t)b * HW_ + (wyi * 4 + (row >> 2)) * 56 + wxi * 4 + (row & 3);
  *(int4*)(attnb + mo * C_ + ch * 8) = v;
}

// ---------------------------------------------------------------------------
// Kernel 4: projection GEMM, fp32 out.
// ---------------------------------------------------------------------------
__global__ __launch_bounds__(256) void proj_gemm(const short* __restrict__ attnb,
    const short* __restrict__ w2b, const float* __restrict__ b2,
    float* __restrict__ out) {
  __shared__ char smem[32768];
  char* As = smem;
  char* Bs = smem + 16384;
  const int t = threadIdx.x, l = t & 63, w = t >> 6;
  const int d = blockIdx.x, xcd = d & 7, i0 = d >> 3;
  const int bn = i0 & 1, bm = (i0 >> 1) * 8 + xcd;
  const int m0 = bm * 128, n0 = bn * 128;
  const int lane = l & 15, kg = l >> 4;
  const int wm = w >> 1, wn = w & 1;

  f32x4 acc[4][4];
#pragma unroll
  for (int i = 0; i < 4; ++i)
#pragma unroll
    for (int j = 0; j < 4; ++j) acc[i][j] = (f32x4){0.f, 0.f, 0.f, 0.f};

  for (int ks = 0; ks < 4; ++ks) {
    const int k0 = ks * 64;
#pragma unroll
    for (int q = 0; q < 4; ++q) {
      const int row = (w * 4 + q) * 8 + (l >> 3);
      const int sc  = (l & 7) ^ (row & 7);
      load_lds16(attnb + (size_t)(m0 + row) * 256 + k0 + sc * 8, As + (w * 4 + q) * 1024);
      load_lds16(w2b   + (size_t)(n0 + row) * 256 + k0 + sc * 8, Bs + (w * 4 + q) * 1024);
    }
    __syncthreads();
#pragma unroll
    for (int s = 0; s < 2; ++s) {
      short8 a[4], b[4];
#pragma unroll
      for (int i = 0; i < 4; ++i) {
        const int r = wm * 64 + i * 16 + lane;
        a[i] = *(const short8*)(As + r * 128 + ((s * 64 + kg * 16) ^ ((r & 7) << 4)));
      }
#pragma unroll
      for (int j = 0; j < 4; ++j) {
        const int r = wn * 64 + j * 16 + lane;
        b[j] = *(const short8*)(Bs + r * 128 + ((s * 64 + kg * 16) ^ ((r & 7) << 4)));
      }
#pragma unroll
      for (int i = 0; i < 4; ++i)
#pragma unroll
        for (int j = 0; j < 4; ++j)
          acc[i][j] = __builtin_amdgcn_mfma_f32_16x16x32_bf16(a[i], b[j], acc[i][j], 0, 0, 0);
    }
    __syncthreads();
  }

#pragma unroll
  for (int j = 0; j < 4; ++j) {
    const int n = n0 + wn * 64 + j * 16 + lane;
    const float bias = b2[n];
#pragma unroll
    for (int i = 0; i < 4; ++i) {
      const int mb = m0 + wm * 64 + i * 16 + kg * 4;
#pragma unroll
      for (int r = 0; r < 4; ++r)
        out[(size_t)(mb + r) * C_ + n] = acc[i][j][r] + bias;
    }
  }
}

// ---------------------------------------------------------------------------
extern "C" void kernel_launch(void* const* d_in, const int* in_sizes, int n_in,
                              void* d_out, int out_size, void* d_ws, size_t ws_size,
                              hipStream_t stream) {
  const float* x   = (const float*)d_in[0];
  const float* w1  = (const float*)d_in[1];
  const float* b1  = (const float*)d_in[2];
  const float* w2  = (const float*)d_in[3];
  const float* b2  = (const float*)d_in[4];
  const float* pos = (const float*)d_in[5];
  float* out = (float*)d_out;

  char* ws = (char*)d_ws;
  short* xt    = (short*)ws;                                  // 100352*256 bf16
  short* qkvb  = (short*)(ws + (size_t)52000000);             // 100352*768 bf16
  short* attnb = (short*)(ws + (size_t)52000000 + 155000000); // 100352*256 bf16
  short* w1p   = (short*)(ws + (size_t)52000000 + 155000000 + 52000000);
  short* w2b   = w1p + 196608;
  float* b1p   = (float*)(w2b + 65536);

  conv_weights<<<768, 256, 0, stream>>>(w1, w2, b1, w1p, w2b, b1p);
  transpose_x <<<1568, 256, 0, stream>>>(x, xt);
  qkv_gemm    <<<4704, 256, 0, stream>>>(xt, w1p, b1p, qkvb);
  win_attn    <<<6272, 512, 0, stream>>>(qkvb, pos, attnb);
  proj_gemm   <<<1568, 256, 0, stream>>>(attnb, w2b, b2, out);
}